// Round 1
// baseline (111.591 us; speedup 1.0000x reference)
//
#include <hip/hip_runtime.h>
#include <math.h>

#define NTH 512

__launch_bounds__(NTH, 2)
__global__ void convcaps_em_kernel(const float* __restrict__ x,
                                   const float* __restrict__ wts,
                                   const float* __restrict__ beta_u,
                                   const float* __restrict__ beta_a,
                                   float* __restrict__ out) {
  constexpr int BK = 288;   // K*K*B_CAPS
  constexpr int CC = 32;    // C_CAPS
  constexpr int PS = 16;    // PSIZE
  constexpr float EPS = 1e-8f;
  constexpr float LAM = 1e-3f;

  __shared__ float v_lds[BK * PS];          // 4608 f (18 KB)
  __shared__ float r_lds[BK * CC];          // 9216 f (36 KB)
  __shared__ float a_lds[BK];               // 288
  __shared__ float rsum_lds[CC];            // 32
  __shared__ float part_lds[16 * CC];       // 512
  __shared__ float muinv_lds[PS * CC * 2];  // 1024 (mu, 0.5/sigma) as [p][c]
  __shared__ float lnac_lds[CC];            // log(a_out) - sum_p lhalf

  const int t = threadIdx.x;
  const int n = blockIdx.x;          // position index: b*64 + oy*8 + ox
  const int b  = n >> 6;
  const int oy = (n >> 3) & 7;
  const int ox = n & 7;

  // ---------------- setup: a_in and v = p_in @ w ----------------
  for (int i = t; i < BK; i += NTH) {
    const int kk = i >> 5, cap = i & 31;
    const int kh = kk / 3, kw = kk - kh * 3;
    const int iy = oy * 2 - 1 + kh, ix = ox * 2 - 1 + kw;
    float val = 0.0f;
    if ((unsigned)iy < 16u && (unsigned)ix < 16u)
      val = x[(((b * 16 + iy) * 16) + ix) * 544 + 512 + cap];
    a_lds[i] = val;
  }
  for (int task = t; task < BK * 4; task += NTH) {
    const int i = task >> 2, p = task & 3;
    const int kk = i >> 5, cap = i & 31;
    const int kh = kk / 3, kw = kk - kh * 3;
    const int iy = oy * 2 - 1 + kh, ix = ox * 2 - 1 + kw;
    float4 vv = make_float4(0.f, 0.f, 0.f, 0.f);
    if ((unsigned)iy < 16u && (unsigned)ix < 16u) {
      const float* px = x + ((((b * 16 + iy) * 16) + ix) * 544 + cap * 16 + p * 4);
      const float4 pin = *reinterpret_cast<const float4*>(px);
      const float* pw = wts + i * 16;
      const float4 w0 = *reinterpret_cast<const float4*>(pw + 0);
      const float4 w1 = *reinterpret_cast<const float4*>(pw + 4);
      const float4 w2 = *reinterpret_cast<const float4*>(pw + 8);
      const float4 w3 = *reinterpret_cast<const float4*>(pw + 12);
      vv.x = pin.x * w0.x + pin.y * w1.x + pin.z * w2.x + pin.w * w3.x;
      vv.y = pin.x * w0.y + pin.y * w1.y + pin.z * w2.y + pin.w * w3.y;
      vv.z = pin.x * w0.z + pin.y * w1.z + pin.z * w2.z + pin.w * w3.z;
      vv.w = pin.x * w0.w + pin.y * w1.w + pin.z * w2.w + pin.w * w3.w;
    }
    *reinterpret_cast<float4*>(&v_lds[i * 16 + p * 4]) = vv;
  }
  __syncthreads();

  const int c32 = t & 31;   // column (A/B/E phases)
  const int g16 = t >> 5;   // 0..15 row-group
  const int cC  = t >> 4;   // 0..31 (phase C)
  const int pC  = t & 15;   // 0..15 (phase C)
  const float bu = beta_u[cC];
  const float ba = beta_a[cC];

  for (int it = 0; it < 3; ++it) {
    // ---- Phase A: rr = (r * a_in) row-normalized over c ----
    for (int pass = 0; pass < 18; ++pass) {
      const int i = pass * 16 + g16;
      float val = (it == 0) ? 0.03125f : r_lds[i * 32 + c32];
      val *= a_lds[i];
      float s = val;
      #pragma unroll
      for (int m = 16; m >= 1; m >>= 1) s += __shfl_xor(s, m, 32);
      r_lds[i * 32 + c32] = val / (s + EPS);
    }
    __syncthreads();

    // ---- Phase B: column sums r_sum[c] = sum_i rr[i][c] ----
    {
      float partial = 0.0f;
      const int base = g16 * 18;
      #pragma unroll 6
      for (int j = 0; j < 18; ++j) partial += r_lds[(base + j) * 32 + c32];
      part_lds[g16 * 32 + c32] = partial;
    }
    __syncthreads();
    if (t < 32) {
      float s = 0.0f;
      #pragma unroll
      for (int g = 0; g < 16; ++g) s += part_lds[g * 32 + t];
      rsum_lds[t] = s;
    }
    __syncthreads();

    // ---- Phase C: mu, sigma, a_out ----
    {
      float s1 = 0.0f, s2 = 0.0f;
      #pragma unroll 4
      for (int i = 0; i < BK; ++i) {
        const float a  = r_lds[i * 32 + cC];
        const float vv = v_lds[i * 16 + pC];
        const float av = a * vv;
        s1 += av;
        s2 += av * vv;
      }
      const float rs = rsum_lds[cC];
      const float D  = rs + EPS;
      const float mu = s1 / D;
      float sig = (s2 - mu * (2.0f * s1 - mu * rs)) / D;
      sig = fmaxf(sig, 0.0f) + EPS;
      const float lhalf = 0.5f * logf(sig);
      float lsum = lhalf;
      #pragma unroll
      for (int m = 8; m >= 1; m >>= 1) lsum += __shfl_xor(lsum, m, 16);
      const float costsum = rs * (16.0f * bu + lsum);
      const float z = LAM * (ba - costsum);
      const float aout = 1.0f / (1.0f + expf(-z));
      if (it < 2) {
        muinv_lds[(pC * 32 + cC) * 2 + 0] = mu;
        muinv_lds[(pC * 32 + cC) * 2 + 1] = 0.5f / sig;
        if (pC == 0) lnac_lds[cC] = logf(aout) - lsum;
      } else {
        out[n * 544 + cC * 16 + pC] = mu;
        if (pC == 0) out[n * 544 + 512 + cC] = aout;
      }
    }
    __syncthreads();

    // ---- Phase E: r = softmax_c( ln a_out - sum_p [ d^2/(2s) + 0.5 ln s ] ) ----
    if (it < 2) {
      float muc[16], isc[16];
      #pragma unroll
      for (int p2 = 0; p2 < 16; ++p2) {
        muc[p2] = muinv_lds[(p2 * 32 + c32) * 2 + 0];
        isc[p2] = muinv_lds[(p2 * 32 + c32) * 2 + 1];
      }
      const float lna = lnac_lds[c32];
      for (int pass = 0; pass < 18; ++pass) {
        const int i = pass * 16 + g16;
        const float4 v0 = *reinterpret_cast<const float4*>(&v_lds[i * 16 + 0]);
        const float4 v1 = *reinterpret_cast<const float4*>(&v_lds[i * 16 + 4]);
        const float4 v2 = *reinterpret_cast<const float4*>(&v_lds[i * 16 + 8]);
        const float4 v3 = *reinterpret_cast<const float4*>(&v_lds[i * 16 + 12]);
        float acc = 0.0f, d;
        d = v0.x - muc[0];  acc += d * d * isc[0];
        d = v0.y - muc[1];  acc += d * d * isc[1];
        d = v0.z - muc[2];  acc += d * d * isc[2];
        d = v0.w - muc[3];  acc += d * d * isc[3];
        d = v1.x - muc[4];  acc += d * d * isc[4];
        d = v1.y - muc[5];  acc += d * d * isc[5];
        d = v1.z - muc[6];  acc += d * d * isc[6];
        d = v1.w - muc[7];  acc += d * d * isc[7];
        d = v2.x - muc[8];  acc += d * d * isc[8];
        d = v2.y - muc[9];  acc += d * d * isc[9];
        d = v2.z - muc[10]; acc += d * d * isc[10];
        d = v2.w - muc[11]; acc += d * d * isc[11];
        d = v3.x - muc[12]; acc += d * d * isc[12];
        d = v3.y - muc[13]; acc += d * d * isc[13];
        d = v3.z - muc[14]; acc += d * d * isc[14];
        d = v3.w - muc[15]; acc += d * d * isc[15];
        const float lnap = lna - acc;
        float mx = lnap;
        #pragma unroll
        for (int m = 16; m >= 1; m >>= 1) mx = fmaxf(mx, __shfl_xor(mx, m, 32));
        const float e = expf(lnap - mx);
        float ssum = e;
        #pragma unroll
        for (int m = 16; m >= 1; m >>= 1) ssum += __shfl_xor(ssum, m, 32);
        r_lds[i * 32 + c32] = e / ssum;
      }
      __syncthreads();
    }
  }
}

extern "C" void kernel_launch(void* const* d_in, const int* in_sizes, int n_in,
                              void* d_out, int out_size, void* d_ws, size_t ws_size,
                              hipStream_t stream) {
  const float* x   = (const float*)d_in[0];
  const float* wts = (const float*)d_in[1];
  const float* bu  = (const float*)d_in[2];
  const float* ba  = (const float*)d_in[3];
  float* out = (float*)d_out;
  hipLaunchKernelGGL(convcaps_em_kernel, dim3(256), dim3(NTH), 0, stream,
                     x, wts, bu, ba, out);
}

// Round 2
// 100.602 us; speedup vs baseline: 1.1092x; 1.1092x over previous
//
#include <hip/hip_runtime.h>
#include <math.h>

#define NTH 1024

__launch_bounds__(NTH, 4)
__global__ void convcaps_em_kernel(const float* __restrict__ x,
                                   const float* __restrict__ wts,
                                   const float* __restrict__ beta_u,
                                   const float* __restrict__ beta_a,
                                   float* __restrict__ out) {
  constexpr int BK = 288;   // K*K*B_CAPS
  constexpr int PS = 16;    // PSIZE
  constexpr float EPS = 1e-8f;
  constexpr float LAM = 1e-3f;

  __shared__ float v_lds[BK * PS];          // 4608 f (18 KB)
  __shared__ float r_lds[BK * 32];          // 9216 f (36 KB)
  __shared__ float a_lds[BK];               // 288
  __shared__ float rsum_lds[32];            // 32
  __shared__ float part_lds[32 * 32];       // 1024 column partials
  __shared__ float cstat_lds[NTH * 2];      // s1,s2 partials for phase C
  __shared__ float muinv_lds[PS * 32 * 2];  // (mu, 0.5/sigma) as [p][c]
  __shared__ float lnac_lds[32];            // log(a_out) - sum_p 0.5*log(sig)

  const int t = threadIdx.x;
  const int n = blockIdx.x;          // position index: b*64 + oy*8 + ox
  const int b  = n >> 6;
  const int oy = (n >> 3) & 7;
  const int ox = n & 7;

  // ---------------- setup: a_in and v = p_in @ w ----------------
  if (t < BK) {
    const int kk = t >> 5, cap = t & 31;
    const int kh = kk / 3, kw = kk - kh * 3;
    const int iy = oy * 2 - 1 + kh, ix = ox * 2 - 1 + kw;
    float val = 0.0f;
    if ((unsigned)iy < 16u && (unsigned)ix < 16u)
      val = x[(((b * 16 + iy) * 16) + ix) * 544 + 512 + cap];
    a_lds[t] = val;
  }
  for (int task = t; task < BK * 4; task += NTH) {
    const int i = task >> 2, p = task & 3;
    const int kk = i >> 5, cap = i & 31;
    const int kh = kk / 3, kw = kk - kh * 3;
    const int iy = oy * 2 - 1 + kh, ix = ox * 2 - 1 + kw;
    float4 vv = make_float4(0.f, 0.f, 0.f, 0.f);
    if ((unsigned)iy < 16u && (unsigned)ix < 16u) {
      const float* px = x + ((((b * 16 + iy) * 16) + ix) * 544 + cap * 16 + p * 4);
      const float4 pin = *reinterpret_cast<const float4*>(px);
      const float* pw = wts + i * 16;
      const float4 w0 = *reinterpret_cast<const float4*>(pw + 0);
      const float4 w1 = *reinterpret_cast<const float4*>(pw + 4);
      const float4 w2 = *reinterpret_cast<const float4*>(pw + 8);
      const float4 w3 = *reinterpret_cast<const float4*>(pw + 12);
      vv.x = pin.x * w0.x + pin.y * w1.x + pin.z * w2.x + pin.w * w3.x;
      vv.y = pin.x * w0.y + pin.y * w1.y + pin.z * w2.y + pin.w * w3.y;
      vv.z = pin.x * w0.z + pin.y * w1.z + pin.z * w2.z + pin.w * w3.z;
      vv.w = pin.x * w0.w + pin.y * w1.w + pin.z * w2.w + pin.w * w3.w;
    }
    *reinterpret_cast<float4*>(&v_lds[i * 16 + p * 4]) = vv;
  }
  __syncthreads();

  const int c32 = t & 31;          // column (A/E phases)
  const int g32 = t >> 5;          // 0..31 row-group
  const int cC  = (t >> 4) & 31;   // phase C / stats column
  const int pC  = t & 15;          // phase C / stats p
  const int hC  = t >> 9;          // 0/1: which half of i-range
  const float bu = beta_u[cC];
  const float ba = beta_a[cC];

  for (int it = 0; it < 3; ++it) {
    // ---- Phase A (+fused B partial): rr = (r * a_in) row-normalized over c ----
    {
      float colsum = 0.0f;
      #pragma unroll 3
      for (int pass = 0; pass < 9; ++pass) {
        const int i = pass * 32 + g32;
        float val = (it == 0) ? 0.03125f : r_lds[i * 32 + c32];
        val *= a_lds[i];
        float s = val;
        #pragma unroll
        for (int m = 16; m >= 1; m >>= 1) s += __shfl_xor(s, m, 32);
        val = val / (s + EPS);
        r_lds[i * 32 + c32] = val;
        colsum += val;
      }
      part_lds[g32 * 32 + c32] = colsum;
    }
    __syncthreads();
    if (t < 32) {
      float s = 0.0f;
      #pragma unroll
      for (int g = 0; g < 32; ++g) s += part_lds[g * 32 + t];
      rsum_lds[t] = s;
    }
    __syncthreads();

    // ---- Phase C: mu, sigma, a_out (2 threads per (c,p) pair) ----
    {
      float s1 = 0.0f, s2 = 0.0f;
      const int ibase = hC * 144;
      #pragma unroll 4
      for (int k = 0; k < 144; ++k) {
        const int i = ibase + k;
        const float a  = r_lds[i * 32 + cC];
        const float vv = v_lds[i * 16 + pC];
        const float av = a * vv;
        s1 += av;
        s2 += av * vv;
      }
      cstat_lds[2 * t + 0] = s1;
      cstat_lds[2 * t + 1] = s2;
    }
    __syncthreads();
    if (t < 512) {
      const float s1 = cstat_lds[2 * t + 0] + cstat_lds[2 * (t + 512) + 0];
      const float s2 = cstat_lds[2 * t + 1] + cstat_lds[2 * (t + 512) + 1];
      const float rs = rsum_lds[cC];
      const float D  = rs + EPS;
      const float mu = s1 / D;
      float sig = (s2 - mu * (2.0f * s1 - mu * rs)) / D;
      sig = fmaxf(sig, 0.0f) + EPS;
      const float lhalf = 0.5f * logf(sig);
      float lsum = lhalf;
      #pragma unroll
      for (int m = 8; m >= 1; m >>= 1) lsum += __shfl_xor(lsum, m, 16);
      const float costsum = rs * (16.0f * bu + lsum);
      const float z = LAM * (ba - costsum);
      const float aout = 1.0f / (1.0f + expf(-z));
      if (it < 2) {
        muinv_lds[(pC * 32 + cC) * 2 + 0] = mu;
        muinv_lds[(pC * 32 + cC) * 2 + 1] = 0.5f / sig;
        if (pC == 0) lnac_lds[cC] = logf(aout) - lsum;
      } else {
        out[n * 544 + cC * 16 + pC] = mu;
        if (pC == 0) out[n * 544 + 512 + cC] = aout;
      }
    }
    __syncthreads();

    // ---- Phase E: r = softmax_c( ln a_out - sum_p [ d^2/(2s) + 0.5 ln s ] ) ----
    if (it < 2) {
      float muc[16], isc[16];
      #pragma unroll
      for (int p2 = 0; p2 < 16; ++p2) {
        muc[p2] = muinv_lds[(p2 * 32 + c32) * 2 + 0];
        isc[p2] = muinv_lds[(p2 * 32 + c32) * 2 + 1];
      }
      const float lna = lnac_lds[c32];
      #pragma unroll 3
      for (int pass = 0; pass < 9; ++pass) {
        const int i = pass * 32 + g32;
        const float4 v0 = *reinterpret_cast<const float4*>(&v_lds[i * 16 + 0]);
        const float4 v1 = *reinterpret_cast<const float4*>(&v_lds[i * 16 + 4]);
        const float4 v2 = *reinterpret_cast<const float4*>(&v_lds[i * 16 + 8]);
        const float4 v3 = *reinterpret_cast<const float4*>(&v_lds[i * 16 + 12]);
        float acc = 0.0f, d;
        d = v0.x - muc[0];  acc += d * d * isc[0];
        d = v0.y - muc[1];  acc += d * d * isc[1];
        d = v0.z - muc[2];  acc += d * d * isc[2];
        d = v0.w - muc[3];  acc += d * d * isc[3];
        d = v1.x - muc[4];  acc += d * d * isc[4];
        d = v1.y - muc[5];  acc += d * d * isc[5];
        d = v1.z - muc[6];  acc += d * d * isc[6];
        d = v1.w - muc[7];  acc += d * d * isc[7];
        d = v2.x - muc[8];  acc += d * d * isc[8];
        d = v2.y - muc[9];  acc += d * d * isc[9];
        d = v2.z - muc[10]; acc += d * d * isc[10];
        d = v2.w - muc[11]; acc += d * d * isc[11];
        d = v3.x - muc[12]; acc += d * d * isc[12];
        d = v3.y - muc[13]; acc += d * d * isc[13];
        d = v3.z - muc[14]; acc += d * d * isc[14];
        d = v3.w - muc[15]; acc += d * d * isc[15];
        const float lnap = lna - acc;
        float mx = lnap;
        #pragma unroll
        for (int m = 16; m >= 1; m >>= 1) mx = fmaxf(mx, __shfl_xor(mx, m, 32));
        const float e = expf(lnap - mx);
        float ssum = e;
        #pragma unroll
        for (int m = 16; m >= 1; m >>= 1) ssum += __shfl_xor(ssum, m, 32);
        r_lds[i * 32 + c32] = e / ssum;
      }
      __syncthreads();
    }
  }
}

extern "C" void kernel_launch(void* const* d_in, const int* in_sizes, int n_in,
                              void* d_out, int out_size, void* d_ws, size_t ws_size,
                              hipStream_t stream) {
  const float* x   = (const float*)d_in[0];
  const float* wts = (const float*)d_in[1];
  const float* bu  = (const float*)d_in[2];
  const float* ba  = (const float*)d_in[3];
  float* out = (float*)d_out;
  hipLaunchKernelGGL(convcaps_em_kernel, dim3(256), dim3(NTH), 0, stream,
                     x, wts, bu, ba, out);
}

// Round 4
// 84.972 us; speedup vs baseline: 1.3133x; 1.1839x over previous
//
#include <hip/hip_runtime.h>
#include <math.h>

#define NTH 1024

__launch_bounds__(NTH, 4)
__global__ void convcaps_em_kernel(const float* __restrict__ x,
                                   const float* __restrict__ wts,
                                   const float* __restrict__ beta_u,
                                   const float* __restrict__ beta_a,
                                   float* __restrict__ out) {
  constexpr int BK = 288;   // K*K*B_CAPS
  constexpr float EPS = 1e-8f;
  constexpr float LAM = 1e-3f;

  __shared__ __align__(16) float v_lds[BK * 16];        // 18 KB
  __shared__ float r_lds[BK * 32];                      // 36 KB (rr, a-folded)
  __shared__ float w_lds[BK];                           // a/(a+eps)
  __shared__ float part_lds[32 * 32];                   // colsum partials [g][c]
  __shared__ float rsum_lds[32];
  __shared__ __align__(16) float cstat_lds[8 * 32 * 4 * 8]; // 32 KB [h][c][pq][s1x4|s2x4]
  __shared__ __align__(8) float muinv_lds[16 * 32 * 2]; // [p][c][mu,0.5/sig]
  __shared__ float lnac_lds[32];                        // log(a_out) - lsum

  const int t = threadIdx.x;
  const int n = blockIdx.x;          // position: b*64 + oy*8 + ox
  const int b  = n >> 6;
  const int oy = (n >> 3) & 7;
  const int ox = n & 7;

  // ---------------- setup: w = a/(a+eps) and v = p_in @ w ----------------
  if (t < BK) {
    const int kk = t >> 5, cap = t & 31;
    const int kh = kk / 3, kw = kk - kh * 3;
    const int iy = oy * 2 - 1 + kh, ix = ox * 2 - 1 + kw;
    float val = 0.0f;
    if ((unsigned)iy < 16u && (unsigned)ix < 16u)
      val = x[(((b * 16 + iy) * 16) + ix) * 544 + 512 + cap];
    w_lds[t] = val / (val + EPS);
  }
  for (int task = t; task < BK * 4; task += NTH) {
    const int i = task >> 2, p = task & 3;
    const int kk = i >> 5, cap = i & 31;
    const int kh = kk / 3, kw = kk - kh * 3;
    const int iy = oy * 2 - 1 + kh, ix = ox * 2 - 1 + kw;
    float4 vv = make_float4(0.f, 0.f, 0.f, 0.f);
    if ((unsigned)iy < 16u && (unsigned)ix < 16u) {
      const float* px = x + ((((b * 16 + iy) * 16) + ix) * 544 + cap * 16 + p * 4);
      const float4 pin = *reinterpret_cast<const float4*>(px);
      const float* pw = wts + i * 16;
      const float4 w0 = *reinterpret_cast<const float4*>(pw + 0);
      const float4 w1 = *reinterpret_cast<const float4*>(pw + 4);
      const float4 w2 = *reinterpret_cast<const float4*>(pw + 8);
      const float4 w3 = *reinterpret_cast<const float4*>(pw + 12);
      vv.x = pin.x * w0.x + pin.y * w1.x + pin.z * w2.x + pin.w * w3.x;
      vv.y = pin.x * w0.y + pin.y * w1.y + pin.z * w2.y + pin.w * w3.y;
      vv.z = pin.x * w0.z + pin.y * w1.z + pin.z * w2.z + pin.w * w3.z;
      vv.w = pin.x * w0.w + pin.y * w1.w + pin.z * w2.w + pin.w * w3.w;
    }
    *reinterpret_cast<float4*>(&v_lds[i * 16 + p * 4]) = vv;
  }
  __syncthreads();

  const int c32 = t & 31;          // column (E phase, C partials)
  const int g32 = t >> 5;          // 0..31 row-group (E phase)

  // r init: r = w/32 (uniform over c), fused colsum partials
  {
    float colsum = 0.0f;
    #pragma unroll
    for (int pass = 0; pass < 9; ++pass) {
      const int i = pass * 32 + g32;
      const float rv = w_lds[i] * 0.03125f;
      r_lds[i * 32 + c32] = rv;
      colsum += rv;
    }
    part_lds[g32 * 32 + c32] = colsum;
  }
  __syncthreads();

  const int pq = (t >> 5) & 3;     // p-quad (C partials)
  const int hC = t >> 7;           // 0..7 i-range (C partials)
  const int cS = (t >> 4) & 31;    // stats column
  const int pS = t & 15;           // stats p
  const float bu = beta_u[cS];
  const float ba = beta_a[cS];

  for (int it = 0; it < 3; ++it) {
    // ---- rsum reduce (from prev E / setup partials), overlapped with C ----
    if (t < 32) {
      float s = 0.0f;
      #pragma unroll
      for (int g = 0; g < 32; ++g) s += part_lds[g * 32 + t];
      rsum_lds[t] = s;
    }
    // ---- Phase C partials: s1/s2 over i-range for (c, p-quad) ----
    {
      float4 s1 = make_float4(0.f, 0.f, 0.f, 0.f);
      float4 s2 = make_float4(0.f, 0.f, 0.f, 0.f);
      const int ib = hC * 36;
      #pragma unroll 6
      for (int k = 0; k < 36; ++k) {
        const int i = ib + k;
        const float r = r_lds[i * 32 + c32];
        const float4 v4 = *reinterpret_cast<const float4*>(&v_lds[i * 16 + pq * 4]);
        s1.x = fmaf(r, v4.x, s1.x); s2.x = fmaf(r * v4.x, v4.x, s2.x);
        s1.y = fmaf(r, v4.y, s1.y); s2.y = fmaf(r * v4.y, v4.y, s2.y);
        s1.z = fmaf(r, v4.z, s1.z); s2.z = fmaf(r * v4.z, v4.z, s2.z);
        s1.w = fmaf(r, v4.w, s1.w); s2.w = fmaf(r * v4.w, v4.w, s2.w);
      }
      float* cs = &cstat_lds[(hC * 128 + c32 * 4 + pq) * 8];
      *reinterpret_cast<float4*>(cs + 0) = s1;
      *reinterpret_cast<float4*>(cs + 4) = s2;
    }
    __syncthreads();

    // ---- Phase C stats: mu, sigma, a_out ----
    if (t < 512) {
      float s1 = 0.0f, s2 = 0.0f;
      #pragma unroll
      for (int h = 0; h < 8; ++h) {
        const float* cs = &cstat_lds[(h * 128 + cS * 4 + (pS >> 2)) * 8 + (pS & 3)];
        s1 += cs[0];
        s2 += cs[4];
      }
      const float rs = rsum_lds[cS];
      const float D  = rs + EPS;
      const float mu = s1 / D;
      float sig = (s2 - mu * (2.0f * s1 - mu * rs)) / D;
      sig = fmaxf(sig, 0.0f) + EPS;
      const float lhalf = 0.5f * logf(sig);
      float lsum = lhalf;
      #pragma unroll
      for (int m = 8; m >= 1; m >>= 1) lsum += __shfl_xor(lsum, m, 16);
      const float z = LAM * (ba - rs * (16.0f * bu + lsum));
      const float aout = 1.0f / (1.0f + expf(-z));
      if (it < 2) {
        *reinterpret_cast<float2*>(&muinv_lds[(pS * 32 + cS) * 2]) =
            make_float2(mu, 0.5f / sig);
        if (pS == 0) lnac_lds[cS] = logf(aout) - lsum;
      } else {
        out[n * 544 + t] = mu;                 // t == cS*16 + pS, coalesced
        if (pS == 0) out[n * 544 + 512 + cS] = aout;
      }
    }

    // ---- Phase E (fused: softmax, fold w, write rr, colsum partials) ----
    if (it < 2) {
      __syncthreads();   // muinv/lnac ready
      float muc[16], isc[16];
      #pragma unroll
      for (int p2 = 0; p2 < 16; ++p2) {
        const float2 mi =
            *reinterpret_cast<const float2*>(&muinv_lds[(p2 * 32 + c32) * 2]);
        muc[p2] = mi.x;
        isc[p2] = mi.y;
      }
      const float lna = lnac_lds[c32];
      float colsum = 0.0f;
      #pragma unroll 3
      for (int pass = 0; pass < 9; ++pass) {
        const int i = pass * 32 + g32;
        const float4 v0 = *reinterpret_cast<const float4*>(&v_lds[i * 16 + 0]);
        const float4 v1 = *reinterpret_cast<const float4*>(&v_lds[i * 16 + 4]);
        const float4 v2 = *reinterpret_cast<const float4*>(&v_lds[i * 16 + 8]);
        const float4 v3 = *reinterpret_cast<const float4*>(&v_lds[i * 16 + 12]);
        float acc = 0.0f, d;
        d = v0.x - muc[0];  acc = fmaf(d * d, isc[0],  acc);
        d = v0.y - muc[1];  acc = fmaf(d * d, isc[1],  acc);
        d = v0.z - muc[2];  acc = fmaf(d * d, isc[2],  acc);
        d = v0.w - muc[3];  acc = fmaf(d * d, isc[3],  acc);
        d = v1.x - muc[4];  acc = fmaf(d * d, isc[4],  acc);
        d = v1.y - muc[5];  acc = fmaf(d * d, isc[5],  acc);
        d = v1.z - muc[6];  acc = fmaf(d * d, isc[6],  acc);
        d = v1.w - muc[7];  acc = fmaf(d * d, isc[7],  acc);
        d = v2.x - muc[8];  acc = fmaf(d * d, isc[8],  acc);
        d = v2.y - muc[9];  acc = fmaf(d * d, isc[9],  acc);
        d = v2.z - muc[10]; acc = fmaf(d * d, isc[10], acc);
        d = v2.w - muc[11]; acc = fmaf(d * d, isc[11], acc);
        d = v3.x - muc[12]; acc = fmaf(d * d, isc[12], acc);
        d = v3.y - muc[13]; acc = fmaf(d * d, isc[13], acc);
        d = v3.z - muc[14]; acc = fmaf(d * d, isc[14], acc);
        d = v3.w - muc[15]; acc = fmaf(d * d, isc[15], acc);
        const float lnap = lna - acc;
        float mx = lnap;
        #pragma unroll
        for (int m = 16; m >= 1; m >>= 1) mx = fmaxf(mx, __shfl_xor(mx, m, 32));
        const float e = expf(lnap - mx);
        float ss = e;
        #pragma unroll
        for (int m = 16; m >= 1; m >>= 1) ss += __shfl_xor(ss, m, 32);
        const float rn = e * (w_lds[i] / ss);   // fold w: rr = softmax * w
        r_lds[i * 32 + c32] = rn;
        colsum += rn;
      }
      part_lds[g32 * 32 + c32] = colsum;
      __syncthreads();
    }
  }
}

extern "C" void kernel_launch(void* const* d_in, const int* in_sizes, int n_in,
                              void* d_out, int out_size, void* d_ws, size_t ws_size,
                              hipStream_t stream) {
  const float* x   = (const float*)d_in[0];
  const float* wts = (const float*)d_in[1];
  const float* bu  = (const float*)d_in[2];
  const float* ba  = (const float*)d_in[3];
  float* out = (float*)d_out;
  hipLaunchKernelGGL(convcaps_em_kernel, dim3(256), dim3(NTH), 0, stream,
                     x, wts, bu, ba, out);
}